// Round 17
// baseline (154.298 us; speedup 1.0000x reference)
//
#include <hip/hip_runtime.h>
#include <hip/hip_bf16.h>

// B=4, T=512, QD=KD=E=256, H=8, L=4, DH=32
// segments {4096,1024,256,64} -> 64-key chunks: seg0 c<64, seg1 c<80, seg2 c<84, seg3 c=84
#define Bn 4
#define Hn 8
#define Tn 512
#define Sn 5440
#define DHn 32
#define En 256

typedef short bf16x8 __attribute__((ext_vector_type(8)));
typedef float f32x4 __attribute__((ext_vector_type(4)));

static __device__ __forceinline__ unsigned short f2bf(float f) {
    union { float f; unsigned u; } c; c.f = f;
    unsigned r = c.u + 0x7fffu + ((c.u >> 16) & 1u);   // RNE
    return (unsigned short)(r >> 16);
}

static __device__ __forceinline__ unsigned int cvtpk(float a, float b) {
    __hip_bfloat162 h = __float22bfloat162_rn(make_float2(a, b));
    unsigned int u; __builtin_memcpy(&u, &h, 4); return u;
}

// ---------------------------------------------------------------------------
// proj_kvq + gates, by blockIdx.z:
//  z=0: k -> ks [B,H,S,DH] bf16 ; z=1: v -> vt [B,H,DH,S] bf16 ;
//  z=2: q -> qs [B,H,T,DH] bf16 (scaled) ; z=3: gates [B,H,T,4]
// ---------------------------------------------------------------------------
__global__ __launch_bounds__(256) void proj_kvq(
    const float* __restrict__ kin, const float* __restrict__ Wk, const float* __restrict__ bk,
    const float* __restrict__ vin, const float* __restrict__ Wv, const float* __restrict__ bv,
    const float* __restrict__ qin, const float* __restrict__ Wq, const float* __restrict__ bq,
    const float* __restrict__ Wl, const float* __restrict__ bl,
    unsigned short* __restrict__ ks_out, unsigned short* __restrict__ vt_out,
    unsigned short* __restrict__ qs_out, float* __restrict__ gates)
{
    __shared__ char smem[20480];            // As/Ws for GEMM; qr/lgs for gates
    int mode = blockIdx.z;
    int tid = threadIdx.x;

    if (mode == 3) {
        // ---- gates: 8 q-rows per logical block, flat id from (x,y) ----
        int fid = blockIdx.x * 2 + blockIdx.y;
        if (fid >= Bn*Tn/8) return;
        float (*qr)[256] = (float(*)[256])smem;            // 8 KB
        float (*lgs)[32] = (float(*)[32])(smem + 8192);    // 1 KB
        int bt0 = fid * 8;
        {
            const float4* src = (const float4*)(qin + (size_t)bt0 * 256);
            float4* dst = (float4*)&qr[0][0];
            dst[tid] = src[tid];
            dst[tid + 256] = src[tid + 256];
        }
        __syncthreads();
        int r = tid >> 5, o = tid & 31;
        float acc = 0.f;
        const float4* w4 = (const float4*)(Wl + (size_t)o * 256);
        const float4* q4 = (const float4*)&qr[r][0];
        #pragma unroll 8
        for (int i = 0; i < 64; i++) {
            float4 w = w4[i]; float4 qq = q4[i];
            acc += qq.x*w.x + qq.y*w.y + qq.z*w.z + qq.w*w.w;
        }
        lgs[r][o] = acc + bl[o];
        __syncthreads();
        if (tid < 64) {
            int rr = tid >> 3, h = tid & 7;
            float x0 = lgs[rr][h*4+0], x1 = lgs[rr][h*4+1], x2 = lgs[rr][h*4+2], x3 = lgs[rr][h*4+3];
            float mx = fmaxf(fmaxf(x0,x1), fmaxf(x2,x3));
            float e0 = __expf(x0-mx), e1 = __expf(x1-mx), e2 = __expf(x2-mx), e3 = __expf(x3-mx);
            float inv = 1.f / (e0+e1+e2+e3);
            int bt = bt0 + rr; int b = bt >> 9, t = bt & 511;
            float* g = gates + (((size_t)b*Hn + h)*Tn + t)*4;
            g[0] = e0*inv; g[1] = e1*inv; g[2] = e2*inv; g[3] = e3*inv;
        }
        return;
    }

    if (mode == 2 && blockIdx.x >= 16) return;

    unsigned short (*As)[40] = (unsigned short(*)[40])smem;            // 10240 B
    unsigned short (*Ws)[40] = (unsigned short(*)[40])(smem + 10240);  // 10240 B

    const float* A    = (mode == 0) ? kin : (mode == 1) ? vin : qin;
    const float* W    = (mode == 0) ? Wk  : (mode == 1) ? Wv  : Wq;
    const float* bias = (mode == 0) ? bk  : (mode == 1) ? bv  : bq;

    int l = tid & 63, wid = tid >> 6;
    int wr = wid >> 1, wc = wid & 1;
    int lr = l & 15, lg = l >> 4;
    int row0 = blockIdx.x * 128, col0 = blockIdx.y * 128;

    f32x4 acc[4][4] = {};

    for (int k0 = 0; k0 < 256; k0 += 32) {
        __syncthreads();
        #pragma unroll
        for (int i = 0; i < 4; i++) {
            int f4 = tid + i*256;
            int r = f4 >> 3, kc = (f4 & 7) * 4;
            float4 v = *(const float4*)(A + (size_t)(row0 + r)*256 + k0 + kc);
            uint2 pk; pk.x = cvtpk(v.x, v.y); pk.y = cvtpk(v.z, v.w);
            *(uint2*)&As[r][kc] = pk;
        }
        #pragma unroll
        for (int i = 0; i < 4; i++) {
            int f4 = tid + i*256;
            int r = f4 >> 3, kc = (f4 & 7) * 4;
            float4 v = *(const float4*)(W + (size_t)(col0 + r)*256 + k0 + kc);
            uint2 pk; pk.x = cvtpk(v.x, v.y); pk.y = cvtpk(v.z, v.w);
            *(uint2*)&Ws[r][kc] = pk;
        }
        __syncthreads();

        bf16x8 af[4], wf[4];
        #pragma unroll
        for (int i = 0; i < 4; i++) {
            af[i] = *(const bf16x8*)&As[wr*64 + i*16 + lr][lg*8];
            wf[i] = *(const bf16x8*)&Ws[wc*64 + i*16 + lr][lg*8];
        }
        #pragma unroll
        for (int i = 0; i < 4; i++)
            #pragma unroll
            for (int j = 0; j < 4; j++)
                acc[i][j] = __builtin_amdgcn_mfma_f32_16x16x32_bf16(af[i], wf[j], acc[i][j], 0, 0, 0);
    }

    const float qscale = 0.17677669529663687f * 1.4426950408889634f;  // dh^-0.5 * log2(e)

    #pragma unroll
    for (int i = 0; i < 4; i++) {
        int m0 = row0 + wr*64 + i*16 + lg*4;
        #pragma unroll
        for (int j = 0; j < 4; j++) {
            int col = col0 + wc*64 + j*16 + lr;
            float bvv = bias[col];
            if (mode == 0) {
                #pragma unroll
                for (int r = 0; r < 4; r++) {
                    int m = m0 + r;
                    int b = m / Sn, s = m - b*Sn;
                    ks_out[(((size_t)b*Hn + (col >> 5))*Sn + s)*DHn + (col & 31)] = f2bf(acc[i][j][r] + bvv);
                }
            } else if (mode == 1) {
                int b = m0 / Sn, s0 = m0 - b*Sn;    // 4-row pack never straddles b
                uint2 pk;
                pk.x = cvtpk(acc[i][j][0] + bvv, acc[i][j][1] + bvv);
                pk.y = cvtpk(acc[i][j][2] + bvv, acc[i][j][3] + bvv);
                *(uint2*)&vt_out[(((size_t)b*Hn + (col >> 5))*DHn + (col & 31))*Sn + s0] = pk;
            } else {
                #pragma unroll
                for (int r = 0; r < 4; r++) {
                    int m = m0 + r;
                    int b = m >> 9, t = m & 511;
                    qs_out[(((size_t)b*Hn + (col >> 5))*Tn + t)*DHn + (col & 31)] = f2bf((acc[i][j][r] + bvv) * qscale);
                }
            }
        }
    }
}

// final projection: out[2048,256] = o_tmp @ Wo^T + bo. 64x64 tiles, 128 blocks.
__global__ __launch_bounds__(256) void proj_out(
    const float* __restrict__ A, const float* __restrict__ W,
    const float* __restrict__ bias, float* __restrict__ out)
{
    __shared__ unsigned short As[64][40];
    __shared__ unsigned short Ws[64][40];

    int tid = threadIdx.x;
    int l = tid & 63, wid = tid >> 6;
    int wr = wid >> 1, wc = wid & 1;
    int lr = l & 15, lg = l >> 4;
    int row0 = blockIdx.x * 64, col0 = blockIdx.y * 64;

    f32x4 acc[2][2] = {};

    for (int k0 = 0; k0 < 256; k0 += 32) {
        __syncthreads();
        #pragma unroll
        for (int i = 0; i < 2; i++) {
            int f4 = tid + i*256;
            int r = f4 >> 3, kc = (f4 & 7) * 4;
            float4 v = *(const float4*)(A + (size_t)(row0 + r)*256 + k0 + kc);
            uint2 pk; pk.x = cvtpk(v.x, v.y); pk.y = cvtpk(v.z, v.w);
            *(uint2*)&As[r][kc] = pk;
        }
        #pragma unroll
        for (int i = 0; i < 2; i++) {
            int f4 = tid + i*256;
            int r = f4 >> 3, kc = (f4 & 7) * 4;
            float4 v = *(const float4*)(W + (size_t)(col0 + r)*256 + k0 + kc);
            uint2 pk; pk.x = cvtpk(v.x, v.y); pk.y = cvtpk(v.z, v.w);
            *(uint2*)&Ws[r][kc] = pk;
        }
        __syncthreads();

        bf16x8 af[2], wf[2];
        #pragma unroll
        for (int i = 0; i < 2; i++) {
            af[i] = *(const bf16x8*)&As[wr*32 + i*16 + lr][lg*8];
            wf[i] = *(const bf16x8*)&Ws[wc*32 + i*16 + lr][lg*8];
        }
        #pragma unroll
        for (int i = 0; i < 2; i++)
            #pragma unroll
            for (int j = 0; j < 2; j++)
                acc[i][j] = __builtin_amdgcn_mfma_f32_16x16x32_bf16(af[i], wf[j], acc[i][j], 0, 0, 0);
    }

    #pragma unroll
    for (int i = 0; i < 2; i++) {
        int m0 = row0 + wr*32 + i*16 + lg*4;
        #pragma unroll
        for (int j = 0; j < 2; j++) {
            int col = col0 + wc*32 + j*16 + lr;
            float bvv = bias[col];
            #pragma unroll
            for (int r = 0; r < 4; r++)
                __builtin_nontemporal_store(acc[i][j][r] + bvv, &out[(size_t)(m0 + r)*256 + col]);
        }
    }
}

// ---------------------------------------------------------------------------
// Fused attention (R12 winner, unchanged): per-wave staged coalesced NT
// stores, no barriers in main loop, direct K/V loads, lcf folded into exp2.
// ---------------------------------------------------------------------------
__global__ __launch_bounds__(256) void attn_fused(
    const unsigned short* __restrict__ qs, const unsigned short* __restrict__ ks,
    const unsigned short* __restrict__ vt, const float* __restrict__ gates,
    float* __restrict__ attn_out, float* __restrict__ o_tmp)
{
    __shared__ char plds[4][2048];          // per-wave P tile [16 rows][64 keys] bf16, XOR-swz
    __shared__ char estw[4][4096];          // per-wave attn stage [16 rows][64 cols] f32, XOR-swz
    __shared__ float lsum[4][4][16];        // [wave][seg][row]
    __shared__ float denom[4][16];          // [seg][row]
    __shared__ float outred[4][16][32];     // [wave][row][d]

    // XCD swizzle: 8 XCDs round-robin on blockIdx; give each XCD 4 whole heads
    int n = blockIdx.x;
    int bh = ((n >> 8) << 3) | (n & 7);     // head group per XCD
    int tt = (n >> 3) & 31;
    int t0 = tt << 4;
    int b = bh >> 3, h = bh & 7;
    int tid = threadIdx.x;
    int l = tid & 63, w = tid >> 6;
    int lr = l & 15, lg = l >> 4;

    bf16x8 aq = *(const bf16x8*)(qs + ((size_t)bh*Tn + t0 + lr)*DHn + lg*8);
    const unsigned short* kb = ks + (size_t)bh * Sn * DHn;
    const unsigned short* vb = vt + (size_t)bh * DHn * Sn;
    const f32x4 fzero = {0.f, 0.f, 0.f, 0.f};

    // ---- pass 1: per-lane exp2 sums per segment (direct loads) ----
    float lp0 = 0.f, lp1 = 0.f, lp2 = 0.f, lp3 = 0.f;
    for (int c = w; c < 85; c += 4) {
        const unsigned short* kc_ = kb + (size_t)c * 64 * DHn;
        bf16x8 kf0 = *(const bf16x8*)(kc_ + (size_t)(lr     )*DHn + lg*8);
        bf16x8 kf1 = *(const bf16x8*)(kc_ + (size_t)(16 + lr)*DHn + lg*8);
        bf16x8 kf2 = *(const bf16x8*)(kc_ + (size_t)(32 + lr)*DHn + lg*8);
        bf16x8 kf3 = *(const bf16x8*)(kc_ + (size_t)(48 + lr)*DHn + lg*8);
        f32x4 s0 = __builtin_amdgcn_mfma_f32_16x16x32_bf16(kf0, aq, fzero, 0, 0, 0);
        f32x4 s1 = __builtin_amdgcn_mfma_f32_16x16x32_bf16(kf1, aq, fzero, 0, 0, 0);
        f32x4 s2 = __builtin_amdgcn_mfma_f32_16x16x32_bf16(kf2, aq, fzero, 0, 0, 0);
        f32x4 s3 = __builtin_amdgcn_mfma_f32_16x16x32_bf16(kf3, aq, fzero, 0, 0, 0);
        float es = exp2f(s0[0]) + exp2f(s0[1]) + exp2f(s0[2]) + exp2f(s0[3])
                 + exp2f(s1[0]) + exp2f(s1[1]) + exp2f(s1[2]) + exp2f(s1[3])
                 + exp2f(s2[0]) + exp2f(s2[1]) + exp2f(s2[2]) + exp2f(s2[3])
                 + exp2f(s3[0]) + exp2f(s3[1]) + exp2f(s3[2]) + exp2f(s3[3]);
        if      (c < 64) lp0 += es;
        else if (c < 80) lp1 += es;
        else if (c < 84) lp2 += es;
        else             lp3 += es;
    }
    {
        float v;
        v = lp0; v += __shfl_xor(v, 16); v += __shfl_xor(v, 32); lp0 = v;
        v = lp1; v += __shfl_xor(v, 16); v += __shfl_xor(v, 32); lp1 = v;
        v = lp2; v += __shfl_xor(v, 16); v += __shfl_xor(v, 32); lp2 = v;
        v = lp3; v += __shfl_xor(v, 16); v += __shfl_xor(v, 32); lp3 = v;
    }
    if (l < 16) {
        lsum[w][0][lr] = lp0; lsum[w][1][lr] = lp1;
        lsum[w][2][lr] = lp2; lsum[w][3][lr] = lp3;
    }
    __syncthreads();
    if (tid < 64) {
        int seg = tid >> 4, row = tid & 15;
        denom[seg][row] = lsum[0][seg][row] + lsum[1][seg][row] + lsum[2][seg][row] + lsum[3][seg][row];
    }
    __syncthreads();

    // fold gate/denom into the exponent: exp2(s)*cf = exp2(s + log2(cf))
    float lcf0, lcf1, lcf2, lcf3;
    {
        const float* g = gates + ((size_t)bh*Tn + t0 + lr)*4;
        lcf0 = __log2f(g[0] / denom[0][lr]);
        lcf1 = __log2f(g[1] / denom[1][lr]);
        lcf2 = __log2f(g[2] / denom[2][lr]);
        lcf3 = __log2f(g[3] / denom[3][lr]);
    }

    // ---- pass 2: recompute; stage in per-wave LDS; coalesced NT store; PV ----
    f32x4 acc0 = fzero, acc1 = fzero;
    char* pbase = plds[w];
    char* ebase = estw[w];
    int swz = (lr & 7) << 4;
    float* abase = attn_out + ((size_t)bh*Tn + t0)*Sn;

    for (int c = w; c < 85; c += 4) {
        float lcf = (c < 64) ? lcf0 : (c < 80) ? lcf1 : (c < 84) ? lcf2 : lcf3;

        const unsigned short* kc_ = kb + (size_t)c * 64 * DHn;
        bf16x8 kf0 = *(const bf16x8*)(kc_ + (size_t)(lr     )*DHn + lg*8);
        bf16x8 kf1 = *(const bf16x8*)(kc_ + (size_t)(16 + lr)*DHn + lg*8);
        bf16x8 kf2 = *(const bf16x8*)(kc_ + (size_t)(32 + lr)*DHn + lg*8);
        bf16x8 kf3 = *(const bf16x8*)(kc_ + (size_t)(48 + lr)*DHn + lg*8);
        bf16x8 vf0 = *(const bf16x8*)(vb + (size_t)(lr     )*Sn + c*64      + lg*8);
        bf16x8 vf1 = *(const bf16x8*)(vb + (size_t)(16 + lr)*Sn + c*64      + lg*8);
        bf16x8 vf2 = *(const bf16x8*)(vb + (size_t)(lr     )*Sn + c*64 + 32 + lg*8);
        bf16x8 vf3 = *(const bf16x8*)(vb + (size_t)(16 + lr)*Sn + c*64 + 32 + lg*8);

        f32x4 s0 = __builtin_amdgcn_mfma_f32_16x16x32_bf16(kf0, aq, fzero, 0, 0, 0);
        f32x4 s1 = __builtin_amdgcn_mfma_f32_16x16x32_bf16(kf1, aq, fzero, 0, 0, 0);
        f32x4 s2 = __builtin_amdgcn_mfma_f32_16x16x32_bf16(kf2, aq, fzero, 0, 0, 0);
        f32x4 s3 = __builtin_amdgcn_mfma_f32_16x16x32_bf16(kf3, aq, fzero, 0, 0, 0);

        // stage attn f32 tile (per-wave, swizzled) + P bf16 tile
        {
            f32x4 av;
            av[0] = exp2f(s0[0]+lcf); av[1] = exp2f(s0[1]+lcf); av[2] = exp2f(s0[2]+lcf); av[3] = exp2f(s0[3]+lcf);
            *(f32x4*)(ebase + ((lr*256 +   0 + lg*16) ^ swz)) = av;
            uint2 pk; pk.x = cvtpk(av[0], av[1]); pk.y = cvtpk(av[2], av[3]);
            *(uint2*)(pbase + ((lr*128 +   0 + lg*8) ^ swz)) = pk;
            av[0] = exp2f(s1[0]+lcf); av[1] = exp2f(s1[1]+lcf); av[2] = exp2f(s1[2]+lcf); av[3] = exp2f(s1[3]+lcf);
            *(f32x4*)(ebase + ((lr*256 +  64 + lg*16) ^ swz)) = av;
            pk.x = cvtpk(av[0], av[1]); pk.y = cvtpk(av[2], av[3]);
            *(uint2*)(pbase + ((lr*128 +  32 + lg*8) ^ swz)) = pk;
            av[0] = exp2f(s2[0]+lcf); av[1] = exp2f(s2[1]+lcf); av[2] = exp2f(s2[2]+lcf); av[3] = exp2f(s2[3]+lcf);
            *(f32x4*)(ebase + ((lr*256 + 128 + lg*16) ^ swz)) = av;
            pk.x = cvtpk(av[0], av[1]); pk.y = cvtpk(av[2], av[3]);
            *(uint2*)(pbase + ((lr*128 +  64 + lg*8) ^ swz)) = pk;
            av[0] = exp2f(s3[0]+lcf); av[1] = exp2f(s3[1]+lcf); av[2] = exp2f(s3[2]+lcf); av[3] = exp2f(s3[3]+lcf);
            *(f32x4*)(ebase + ((lr*256 + 192 + lg*16) ^ swz)) = av;
            pk.x = cvtpk(av[0], av[1]); pk.y = cvtpk(av[2], av[3]);
            *(uint2*)(pbase + ((lr*128 +  96 + lg*8) ^ swz)) = pk;
        }

        __builtin_amdgcn_s_setprio(1);
        {
            bf16x8 pa0 = *(const bf16x8*)(pbase + ((lr*128 +      lg*16) ^ swz));
            acc0 = __builtin_amdgcn_mfma_f32_16x16x32_bf16(pa0, vf0, acc0, 0, 0, 0);
            acc1 = __builtin_amdgcn_mfma_f32_16x16x32_bf16(pa0, vf1, acc1, 0, 0, 0);
            bf16x8 pa1 = *(const bf16x8*)(pbase + ((lr*128 + 64 + lg*16) ^ swz));
            acc0 = __builtin_amdgcn_mfma_f32_16x16x32_bf16(pa1, vf2, acc0, 0, 0, 0);
            acc1 = __builtin_amdgcn_mfma_f32_16x16x32_bf16(pa1, vf3, acc1, 0, 0, 0);
        }
        __builtin_amdgcn_s_setprio(0);

        // wave-local coalesced NT store: 4 instrs, each 4 rows x 256B bursts
        #pragma unroll
        for (int i = 0; i < 4; i++) {
            int row = i*4 + lg;
            f32x4 vv = *(const f32x4*)(ebase + ((row*256 + lr*16) ^ ((row & 7) << 4)));
            __builtin_nontemporal_store(vv, (f32x4*)(abase + (size_t)row*Sn + c*64 + lr*4));
        }
    }

    // cross-wave PV reduction
    #pragma unroll
    for (int r = 0; r < 4; r++) {
        outred[w][4*lg + r][lr]      = acc0[r];
        outred[w][4*lg + r][16 + lr] = acc1[r];
    }
    __syncthreads();
    #pragma unroll
    for (int i = 0; i < 2; i++) {
        int idx = tid + i*256;
        int row = idx >> 5, d = idx & 31;
        float sum = outred[0][row][d] + outred[1][row][d] + outred[2][row][d] + outred[3][row][d];
        __builtin_nontemporal_store(sum, &o_tmp[((size_t)(b*Tn + t0 + row))*En + h*DHn + d]);
    }
}

// ---------------------------------------------------------------------------
extern "C" void kernel_launch(void* const* d_in, const int* in_sizes, int n_in,
                              void* d_out, int out_size, void* d_ws, size_t ws_size,
                              hipStream_t stream)
{
    const float* q  = (const float*)d_in[0];
    const float* k  = (const float*)d_in[1];
    const float* v  = (const float*)d_in[2];
    const float* Wq = (const float*)d_in[3];
    const float* bq = (const float*)d_in[4];
    const float* Wk = (const float*)d_in[5];
    const float* bk = (const float*)d_in[6];
    const float* Wv = (const float*)d_in[7];
    const float* bv = (const float*)d_in[8];
    const float* Wo = (const float*)d_in[9];
    const float* bo = (const float*)d_in[10];
    const float* Wl = (const float*)d_in[11];
    const float* bl = (const float*)d_in[12];

    float* out  = (float*)d_out;                         // [B,T,256]
    float* attn = out + (size_t)Bn*Tn*256;               // [B,H,T,S]

    // workspace: qs | ks | vt | gates | o_tmp
    char* ws = (char*)d_ws;
    unsigned short* qs    = (unsigned short*)ws;                             // 1 MB
    unsigned short* ksb   = (unsigned short*)(ws + (1u<<20));                // 11,141,120 B
    unsigned short* vtb   = (unsigned short*)(ws + (1u<<20) + 11141120u);
    float*          gates = (float*)(ws + (1u<<20) + 2u*11141120u);          // 262,144 B
    float*          o_tmp = (float*)(ws + (1u<<20) + 2u*11141120u + 262144u);

    proj_kvq<<<dim3((Bn*Sn)/128, 2, 4), 256, 0, stream>>>(
        k, Wk, bk, v, Wv, bv, q, Wq, bq, Wl, bl, ksb, vtb, qs, gates);
    attn_fused<<<Bn*Hn*(Tn/16), 256, 0, stream>>>(qs, ksb, vtb, gates, attn, o_tmp);
    proj_out<<<dim3((Bn*Tn)/64, 4), 256, 0, stream>>>(o_tmp, Wo, bo, out);
}

// Round 18
// 148.575 us; speedup vs baseline: 1.0385x; 1.0385x over previous
//
#include <hip/hip_runtime.h>
#include <hip/hip_bf16.h>

// B=4, T=512, QD=KD=E=256, H=8, L=4, DH=32
// segments {4096,1024,256,64} -> 64-key chunks: seg0 c<64, seg1 c<80, seg2 c<84, seg3 c=84
#define Bn 4
#define Hn 8
#define Tn 512
#define Sn 5440
#define DHn 32
#define En 256

typedef short bf16x8 __attribute__((ext_vector_type(8)));
typedef float f32x4 __attribute__((ext_vector_type(4)));

static __device__ __forceinline__ unsigned short f2bf(float f) {
    union { float f; unsigned u; } c; c.f = f;
    unsigned r = c.u + 0x7fffu + ((c.u >> 16) & 1u);   // RNE
    return (unsigned short)(r >> 16);
}

static __device__ __forceinline__ unsigned int cvtpk(float a, float b) {
    __hip_bfloat162 h = __float22bfloat162_rn(make_float2(a, b));
    unsigned int u; __builtin_memcpy(&u, &h, 4); return u;
}

// ---------------------------------------------------------------------------
// proj_kvq + gates, by blockIdx.z:
//  z=0: k -> ks [B,H,S,DH] bf16 ; z=1: v -> vt [B,H,DH,S] bf16 ;
//  z=2: q -> qs [B,H,T,DH] bf16 (scaled) ; z=3: gates [B,H,T,4]
// ---------------------------------------------------------------------------
__global__ __launch_bounds__(256) void proj_kvq(
    const float* __restrict__ kin, const float* __restrict__ Wk, const float* __restrict__ bk,
    const float* __restrict__ vin, const float* __restrict__ Wv, const float* __restrict__ bv,
    const float* __restrict__ qin, const float* __restrict__ Wq, const float* __restrict__ bq,
    const float* __restrict__ Wl, const float* __restrict__ bl,
    unsigned short* __restrict__ ks_out, unsigned short* __restrict__ vt_out,
    unsigned short* __restrict__ qs_out, float* __restrict__ gates)
{
    __shared__ char smem[20480];            // As/Ws for GEMM; qr/lgs for gates
    int mode = blockIdx.z;
    int tid = threadIdx.x;

    if (mode == 3) {
        // ---- gates: 8 q-rows per logical block, flat id from (x,y) ----
        int fid = blockIdx.x * 2 + blockIdx.y;
        if (fid >= Bn*Tn/8) return;
        float (*qr)[256] = (float(*)[256])smem;            // 8 KB
        float (*lgs)[32] = (float(*)[32])(smem + 8192);    // 1 KB
        int bt0 = fid * 8;
        {
            const float4* src = (const float4*)(qin + (size_t)bt0 * 256);
            float4* dst = (float4*)&qr[0][0];
            dst[tid] = src[tid];
            dst[tid + 256] = src[tid + 256];
        }
        __syncthreads();
        int r = tid >> 5, o = tid & 31;
        float acc = 0.f;
        const float4* w4 = (const float4*)(Wl + (size_t)o * 256);
        const float4* q4 = (const float4*)&qr[r][0];
        #pragma unroll 8
        for (int i = 0; i < 64; i++) {
            float4 w = w4[i]; float4 qq = q4[i];
            acc += qq.x*w.x + qq.y*w.y + qq.z*w.z + qq.w*w.w;
        }
        lgs[r][o] = acc + bl[o];
        __syncthreads();
        if (tid < 64) {
            int rr = tid >> 3, h = tid & 7;
            float x0 = lgs[rr][h*4+0], x1 = lgs[rr][h*4+1], x2 = lgs[rr][h*4+2], x3 = lgs[rr][h*4+3];
            float mx = fmaxf(fmaxf(x0,x1), fmaxf(x2,x3));
            float e0 = __expf(x0-mx), e1 = __expf(x1-mx), e2 = __expf(x2-mx), e3 = __expf(x3-mx);
            float inv = 1.f / (e0+e1+e2+e3);
            int bt = bt0 + rr; int b = bt >> 9, t = bt & 511;
            float* g = gates + (((size_t)b*Hn + h)*Tn + t)*4;
            g[0] = e0*inv; g[1] = e1*inv; g[2] = e2*inv; g[3] = e3*inv;
        }
        return;
    }

    if (mode == 2 && blockIdx.x >= 16) return;

    unsigned short (*As)[40] = (unsigned short(*)[40])smem;            // 10240 B
    unsigned short (*Ws)[40] = (unsigned short(*)[40])(smem + 10240);  // 10240 B

    const float* A    = (mode == 0) ? kin : (mode == 1) ? vin : qin;
    const float* W    = (mode == 0) ? Wk  : (mode == 1) ? Wv  : Wq;
    const float* bias = (mode == 0) ? bk  : (mode == 1) ? bv  : bq;

    int l = tid & 63, wid = tid >> 6;
    int wr = wid >> 1, wc = wid & 1;
    int lr = l & 15, lg = l >> 4;
    int row0 = blockIdx.x * 128, col0 = blockIdx.y * 128;

    f32x4 acc[4][4] = {};

    for (int k0 = 0; k0 < 256; k0 += 32) {
        __syncthreads();
        #pragma unroll
        for (int i = 0; i < 4; i++) {
            int f4 = tid + i*256;
            int r = f4 >> 3, kc = (f4 & 7) * 4;
            float4 v = *(const float4*)(A + (size_t)(row0 + r)*256 + k0 + kc);
            uint2 pk; pk.x = cvtpk(v.x, v.y); pk.y = cvtpk(v.z, v.w);
            *(uint2*)&As[r][kc] = pk;
        }
        #pragma unroll
        for (int i = 0; i < 4; i++) {
            int f4 = tid + i*256;
            int r = f4 >> 3, kc = (f4 & 7) * 4;
            float4 v = *(const float4*)(W + (size_t)(col0 + r)*256 + k0 + kc);
            uint2 pk; pk.x = cvtpk(v.x, v.y); pk.y = cvtpk(v.z, v.w);
            *(uint2*)&Ws[r][kc] = pk;
        }
        __syncthreads();

        bf16x8 af[4], wf[4];
        #pragma unroll
        for (int i = 0; i < 4; i++) {
            af[i] = *(const bf16x8*)&As[wr*64 + i*16 + lr][lg*8];
            wf[i] = *(const bf16x8*)&Ws[wc*64 + i*16 + lr][lg*8];
        }
        #pragma unroll
        for (int i = 0; i < 4; i++)
            #pragma unroll
            for (int j = 0; j < 4; j++)
                acc[i][j] = __builtin_amdgcn_mfma_f32_16x16x32_bf16(af[i], wf[j], acc[i][j], 0, 0, 0);
    }

    const float qscale = 0.17677669529663687f * 1.4426950408889634f;  // dh^-0.5 * log2(e)

    #pragma unroll
    for (int i = 0; i < 4; i++) {
        int m0 = row0 + wr*64 + i*16 + lg*4;
        #pragma unroll
        for (int j = 0; j < 4; j++) {
            int col = col0 + wc*64 + j*16 + lr;
            float bvv = bias[col];
            if (mode == 0) {
                #pragma unroll
                for (int r = 0; r < 4; r++) {
                    int m = m0 + r;
                    int b = m / Sn, s = m - b*Sn;
                    ks_out[(((size_t)b*Hn + (col >> 5))*Sn + s)*DHn + (col & 31)] = f2bf(acc[i][j][r] + bvv);
                }
            } else if (mode == 1) {
                int b = m0 / Sn, s0 = m0 - b*Sn;    // 4-row pack never straddles b
                uint2 pk;
                pk.x = cvtpk(acc[i][j][0] + bvv, acc[i][j][1] + bvv);
                pk.y = cvtpk(acc[i][j][2] + bvv, acc[i][j][3] + bvv);
                *(uint2*)&vt_out[(((size_t)b*Hn + (col >> 5))*DHn + (col & 31))*Sn + s0] = pk;
            } else {
                #pragma unroll
                for (int r = 0; r < 4; r++) {
                    int m = m0 + r;
                    int b = m >> 9, t = m & 511;
                    qs_out[(((size_t)b*Hn + (col >> 5))*Tn + t)*DHn + (col & 31)] = f2bf((acc[i][j][r] + bvv) * qscale);
                }
            }
        }
    }
}

// final projection: out[M,256] = o_tmp @ Wo^T + bo, fp32 out (nt stores)
__global__ __launch_bounds__(256) void proj_out(
    const float* __restrict__ A, const float* __restrict__ W,
    const float* __restrict__ bias, float* __restrict__ out)
{
    __shared__ unsigned short As[128][40];
    __shared__ unsigned short Ws[128][40];

    int tid = threadIdx.x;
    int l = tid & 63, wid = tid >> 6;
    int wr = wid >> 1, wc = wid & 1;
    int lr = l & 15, lg = l >> 4;
    int row0 = blockIdx.x * 128, col0 = blockIdx.y * 128;

    f32x4 acc[4][4] = {};

    for (int k0 = 0; k0 < 256; k0 += 32) {
        __syncthreads();
        #pragma unroll
        for (int i = 0; i < 4; i++) {
            int f4 = tid + i*256;
            int r = f4 >> 3, kc = (f4 & 7) * 4;
            float4 v = *(const float4*)(A + (size_t)(row0 + r)*256 + k0 + kc);
            uint2 pk; pk.x = cvtpk(v.x, v.y); pk.y = cvtpk(v.z, v.w);
            *(uint2*)&As[r][kc] = pk;
        }
        #pragma unroll
        for (int i = 0; i < 4; i++) {
            int f4 = tid + i*256;
            int r = f4 >> 3, kc = (f4 & 7) * 4;
            float4 v = *(const float4*)(W + (size_t)(col0 + r)*256 + k0 + kc);
            uint2 pk; pk.x = cvtpk(v.x, v.y); pk.y = cvtpk(v.z, v.w);
            *(uint2*)&Ws[r][kc] = pk;
        }
        __syncthreads();

        bf16x8 af[4], wf[4];
        #pragma unroll
        for (int i = 0; i < 4; i++) {
            af[i] = *(const bf16x8*)&As[wr*64 + i*16 + lr][lg*8];
            wf[i] = *(const bf16x8*)&Ws[wc*64 + i*16 + lr][lg*8];
        }
        #pragma unroll
        for (int i = 0; i < 4; i++)
            #pragma unroll
            for (int j = 0; j < 4; j++)
                acc[i][j] = __builtin_amdgcn_mfma_f32_16x16x32_bf16(af[i], wf[j], acc[i][j], 0, 0, 0);
    }

    #pragma unroll
    for (int i = 0; i < 4; i++) {
        int m0 = row0 + wr*64 + i*16 + lg*4;
        #pragma unroll
        for (int j = 0; j < 4; j++) {
            int col = col0 + wc*64 + j*16 + lr;
            float bvv = bias[col];
            #pragma unroll
            for (int r = 0; r < 4; r++)
                __builtin_nontemporal_store(acc[i][j][r] + bvv, &out[(size_t)(m0 + r)*256 + col]);
        }
    }
}

// ---------------------------------------------------------------------------
// Fused attention (R12 winner, unchanged): per-wave staged coalesced NT
// stores, no barriers in main loop, direct K/V loads, lcf folded into exp2.
// ---------------------------------------------------------------------------
__global__ __launch_bounds__(256) void attn_fused(
    const unsigned short* __restrict__ qs, const unsigned short* __restrict__ ks,
    const unsigned short* __restrict__ vt, const float* __restrict__ gates,
    float* __restrict__ attn_out, float* __restrict__ o_tmp)
{
    __shared__ char plds[4][2048];          // per-wave P tile [16 rows][64 keys] bf16, XOR-swz
    __shared__ char estw[4][4096];          // per-wave attn stage [16 rows][64 cols] f32, XOR-swz
    __shared__ float lsum[4][4][16];        // [wave][seg][row]
    __shared__ float denom[4][16];          // [seg][row]
    __shared__ float outred[4][16][32];     // [wave][row][d]

    // XCD swizzle: 8 XCDs round-robin on blockIdx; give each XCD 4 whole heads
    int n = blockIdx.x;
    int bh = ((n >> 8) << 3) | (n & 7);     // head group per XCD
    int tt = (n >> 3) & 31;
    int t0 = tt << 4;
    int b = bh >> 3, h = bh & 7;
    int tid = threadIdx.x;
    int l = tid & 63, w = tid >> 6;
    int lr = l & 15, lg = l >> 4;

    bf16x8 aq = *(const bf16x8*)(qs + ((size_t)bh*Tn + t0 + lr)*DHn + lg*8);
    const unsigned short* kb = ks + (size_t)bh * Sn * DHn;
    const unsigned short* vb = vt + (size_t)bh * DHn * Sn;
    const f32x4 fzero = {0.f, 0.f, 0.f, 0.f};

    // ---- pass 1: per-lane exp2 sums per segment (direct loads) ----
    float lp0 = 0.f, lp1 = 0.f, lp2 = 0.f, lp3 = 0.f;
    for (int c = w; c < 85; c += 4) {
        const unsigned short* kc_ = kb + (size_t)c * 64 * DHn;
        bf16x8 kf0 = *(const bf16x8*)(kc_ + (size_t)(lr     )*DHn + lg*8);
        bf16x8 kf1 = *(const bf16x8*)(kc_ + (size_t)(16 + lr)*DHn + lg*8);
        bf16x8 kf2 = *(const bf16x8*)(kc_ + (size_t)(32 + lr)*DHn + lg*8);
        bf16x8 kf3 = *(const bf16x8*)(kc_ + (size_t)(48 + lr)*DHn + lg*8);
        f32x4 s0 = __builtin_amdgcn_mfma_f32_16x16x32_bf16(kf0, aq, fzero, 0, 0, 0);
        f32x4 s1 = __builtin_amdgcn_mfma_f32_16x16x32_bf16(kf1, aq, fzero, 0, 0, 0);
        f32x4 s2 = __builtin_amdgcn_mfma_f32_16x16x32_bf16(kf2, aq, fzero, 0, 0, 0);
        f32x4 s3 = __builtin_amdgcn_mfma_f32_16x16x32_bf16(kf3, aq, fzero, 0, 0, 0);
        float es = exp2f(s0[0]) + exp2f(s0[1]) + exp2f(s0[2]) + exp2f(s0[3])
                 + exp2f(s1[0]) + exp2f(s1[1]) + exp2f(s1[2]) + exp2f(s1[3])
                 + exp2f(s2[0]) + exp2f(s2[1]) + exp2f(s2[2]) + exp2f(s2[3])
                 + exp2f(s3[0]) + exp2f(s3[1]) + exp2f(s3[2]) + exp2f(s3[3]);
        if      (c < 64) lp0 += es;
        else if (c < 80) lp1 += es;
        else if (c < 84) lp2 += es;
        else             lp3 += es;
    }
    {
        float v;
        v = lp0; v += __shfl_xor(v, 16); v += __shfl_xor(v, 32); lp0 = v;
        v = lp1; v += __shfl_xor(v, 16); v += __shfl_xor(v, 32); lp1 = v;
        v = lp2; v += __shfl_xor(v, 16); v += __shfl_xor(v, 32); lp2 = v;
        v = lp3; v += __shfl_xor(v, 16); v += __shfl_xor(v, 32); lp3 = v;
    }
    if (l < 16) {
        lsum[w][0][lr] = lp0; lsum[w][1][lr] = lp1;
        lsum[w][2][lr] = lp2; lsum[w][3][lr] = lp3;
    }
    __syncthreads();
    if (tid < 64) {
        int seg = tid >> 4, row = tid & 15;
        denom[seg][row] = lsum[0][seg][row] + lsum[1][seg][row] + lsum[2][seg][row] + lsum[3][seg][row];
    }
    __syncthreads();

    // fold gate/denom into the exponent: exp2(s)*cf = exp2(s + log2(cf))
    float lcf0, lcf1, lcf2, lcf3;
    {
        const float* g = gates + ((size_t)bh*Tn + t0 + lr)*4;
        lcf0 = __log2f(g[0] / denom[0][lr]);
        lcf1 = __log2f(g[1] / denom[1][lr]);
        lcf2 = __log2f(g[2] / denom[2][lr]);
        lcf3 = __log2f(g[3] / denom[3][lr]);
    }

    // ---- pass 2: recompute; stage in per-wave LDS; coalesced NT store; PV ----
    f32x4 acc0 = fzero, acc1 = fzero;
    char* pbase = plds[w];
    char* ebase = estw[w];
    int swz = (lr & 7) << 4;
    float* abase = attn_out + ((size_t)bh*Tn + t0)*Sn;

    for (int c = w; c < 85; c += 4) {
        float lcf = (c < 64) ? lcf0 : (c < 80) ? lcf1 : (c < 84) ? lcf2 : lcf3;

        const unsigned short* kc_ = kb + (size_t)c * 64 * DHn;
        bf16x8 kf0 = *(const bf16x8*)(kc_ + (size_t)(lr     )*DHn + lg*8);
        bf16x8 kf1 = *(const bf16x8*)(kc_ + (size_t)(16 + lr)*DHn + lg*8);
        bf16x8 kf2 = *(const bf16x8*)(kc_ + (size_t)(32 + lr)*DHn + lg*8);
        bf16x8 kf3 = *(const bf16x8*)(kc_ + (size_t)(48 + lr)*DHn + lg*8);
        bf16x8 vf0 = *(const bf16x8*)(vb + (size_t)(lr     )*Sn + c*64      + lg*8);
        bf16x8 vf1 = *(const bf16x8*)(vb + (size_t)(16 + lr)*Sn + c*64      + lg*8);
        bf16x8 vf2 = *(const bf16x8*)(vb + (size_t)(lr     )*Sn + c*64 + 32 + lg*8);
        bf16x8 vf3 = *(const bf16x8*)(vb + (size_t)(16 + lr)*Sn + c*64 + 32 + lg*8);

        f32x4 s0 = __builtin_amdgcn_mfma_f32_16x16x32_bf16(kf0, aq, fzero, 0, 0, 0);
        f32x4 s1 = __builtin_amdgcn_mfma_f32_16x16x32_bf16(kf1, aq, fzero, 0, 0, 0);
        f32x4 s2 = __builtin_amdgcn_mfma_f32_16x16x32_bf16(kf2, aq, fzero, 0, 0, 0);
        f32x4 s3 = __builtin_amdgcn_mfma_f32_16x16x32_bf16(kf3, aq, fzero, 0, 0, 0);

        // stage attn f32 tile (per-wave, swizzled) + P bf16 tile
        {
            f32x4 av;
            av[0] = exp2f(s0[0]+lcf); av[1] = exp2f(s0[1]+lcf); av[2] = exp2f(s0[2]+lcf); av[3] = exp2f(s0[3]+lcf);
            *(f32x4*)(ebase + ((lr*256 +   0 + lg*16) ^ swz)) = av;
            uint2 pk; pk.x = cvtpk(av[0], av[1]); pk.y = cvtpk(av[2], av[3]);
            *(uint2*)(pbase + ((lr*128 +   0 + lg*8) ^ swz)) = pk;
            av[0] = exp2f(s1[0]+lcf); av[1] = exp2f(s1[1]+lcf); av[2] = exp2f(s1[2]+lcf); av[3] = exp2f(s1[3]+lcf);
            *(f32x4*)(ebase + ((lr*256 +  64 + lg*16) ^ swz)) = av;
            pk.x = cvtpk(av[0], av[1]); pk.y = cvtpk(av[2], av[3]);
            *(uint2*)(pbase + ((lr*128 +  32 + lg*8) ^ swz)) = pk;
            av[0] = exp2f(s2[0]+lcf); av[1] = exp2f(s2[1]+lcf); av[2] = exp2f(s2[2]+lcf); av[3] = exp2f(s2[3]+lcf);
            *(f32x4*)(ebase + ((lr*256 + 128 + lg*16) ^ swz)) = av;
            pk.x = cvtpk(av[0], av[1]); pk.y = cvtpk(av[2], av[3]);
            *(uint2*)(pbase + ((lr*128 +  64 + lg*8) ^ swz)) = pk;
            av[0] = exp2f(s3[0]+lcf); av[1] = exp2f(s3[1]+lcf); av[2] = exp2f(s3[2]+lcf); av[3] = exp2f(s3[3]+lcf);
            *(f32x4*)(ebase + ((lr*256 + 192 + lg*16) ^ swz)) = av;
            pk.x = cvtpk(av[0], av[1]); pk.y = cvtpk(av[2], av[3]);
            *(uint2*)(pbase + ((lr*128 +  96 + lg*8) ^ swz)) = pk;
        }

        __builtin_amdgcn_s_setprio(1);
        {
            bf16x8 pa0 = *(const bf16x8*)(pbase + ((lr*128 +      lg*16) ^ swz));
            acc0 = __builtin_amdgcn_mfma_f32_16x16x32_bf16(pa0, vf0, acc0, 0, 0, 0);
            acc1 = __builtin_amdgcn_mfma_f32_16x16x32_bf16(pa0, vf1, acc1, 0, 0, 0);
            bf16x8 pa1 = *(const bf16x8*)(pbase + ((lr*128 + 64 + lg*16) ^ swz));
            acc0 = __builtin_amdgcn_mfma_f32_16x16x32_bf16(pa1, vf2, acc0, 0, 0, 0);
            acc1 = __builtin_amdgcn_mfma_f32_16x16x32_bf16(pa1, vf3, acc1, 0, 0, 0);
        }
        __builtin_amdgcn_s_setprio(0);

        // wave-local coalesced NT store: 4 instrs, each 4 rows x 256B bursts
        #pragma unroll
        for (int i = 0; i < 4; i++) {
            int row = i*4 + lg;
            f32x4 vv = *(const f32x4*)(ebase + ((row*256 + lr*16) ^ ((row & 7) << 4)));
            __builtin_nontemporal_store(vv, (f32x4*)(abase + (size_t)row*Sn + c*64 + lr*4));
        }
    }

    // cross-wave PV reduction
    #pragma unroll
    for (int r = 0; r < 4; r++) {
        outred[w][4*lg + r][lr]      = acc0[r];
        outred[w][4*lg + r][16 + lr] = acc1[r];
    }
    __syncthreads();
    #pragma unroll
    for (int i = 0; i < 2; i++) {
        int idx = tid + i*256;
        int row = idx >> 5, d = idx & 31;
        float sum = outred[0][row][d] + outred[1][row][d] + outred[2][row][d] + outred[3][row][d];
        __builtin_nontemporal_store(sum, &o_tmp[((size_t)(b*Tn + t0 + row))*En + h*DHn + d]);
    }
}

// ---------------------------------------------------------------------------
extern "C" void kernel_launch(void* const* d_in, const int* in_sizes, int n_in,
                              void* d_out, int out_size, void* d_ws, size_t ws_size,
                              hipStream_t stream)
{
    const float* q  = (const float*)d_in[0];
    const float* k  = (const float*)d_in[1];
    const float* v  = (const float*)d_in[2];
    const float* Wq = (const float*)d_in[3];
    const float* bq = (const float*)d_in[4];
    const float* Wk = (const float*)d_in[5];
    const float* bk = (const float*)d_in[6];
    const float* Wv = (const float*)d_in[7];
    const float* bv = (const float*)d_in[8];
    const float* Wo = (const float*)d_in[9];
    const float* bo = (const float*)d_in[10];
    const float* Wl = (const float*)d_in[11];
    const float* bl = (const float*)d_in[12];

    float* out  = (float*)d_out;                         // [B,T,256]
    float* attn = out + (size_t)Bn*Tn*256;               // [B,H,T,S]

    // workspace: qs | ks | vt | gates | o_tmp
    char* ws = (char*)d_ws;
    unsigned short* qs    = (unsigned short*)ws;                             // 1 MB
    unsigned short* ksb   = (unsigned short*)(ws + (1u<<20));                // 11,141,120 B
    unsigned short* vtb   = (unsigned short*)(ws + (1u<<20) + 11141120u);
    float*          gates = (float*)(ws + (1u<<20) + 2u*11141120u);          // 262,144 B
    float*          o_tmp = (float*)(ws + (1u<<20) + 2u*11141120u + 262144u);

    proj_kvq<<<dim3((Bn*Sn)/128, 2, 4), 256, 0, stream>>>(
        k, Wk, bk, v, Wv, bv, q, Wq, bq, Wl, bl, ksb, vtb, qs, gates);
    attn_fused<<<Bn*Hn*(Tn/16), 256, 0, stream>>>(qs, ksb, vtb, gates, attn, o_tmp);
    proj_out<<<dim3((Bn*Tn)/128, 2), 256, 0, stream>>>(o_tmp, Wo, bo, out);
}